// Round 1
// baseline (1683.680 us; speedup 1.0000x reference)
//
#include <hip/hip_runtime.h>

// Problem constants
#define B_   2
#define N_   192
#define DIM_ 512
#define H_   8
#define DH_  64
#define M_   (B_*N_)        // 384 token rows
#define QKV_ROWS 2560       // 512 q + 1024 kcat + 1024 vcat
#define EPS_RMS 1.1920929e-7f
#define SCALE_ 0.125f       // DH^-0.5
#define ARR_ (B_*H_*N_*DH_) // 196608 elems per staged array

// ---------- helpers ----------
__device__ __forceinline__ unsigned short f2bf(float f) {
  unsigned int u = __float_as_uint(f);
  unsigned int r = (u + 0x7fffu + ((u >> 16) & 1u)) >> 16;  // RNE
  return (unsigned short)r;
}
__device__ __forceinline__ float bf16_lo(unsigned int u) { return __uint_as_float(u << 16); }
__device__ __forceinline__ float bf16_hi(unsigned int u) { return __uint_as_float(u & 0xffff0000u); }
__device__ __forceinline__ float rl(float v, int l) {
  return __uint_as_float((unsigned int)__builtin_amdgcn_readlane((int)__float_as_uint(v), l));
}
__device__ __forceinline__ float waveMax(float x) {
  #pragma unroll
  for (int off = 32; off; off >>= 1) x = fmaxf(x, __shfl_xor(x, off, 64));
  return x;
}
__device__ __forceinline__ float waveSum(float x) {
  #pragma unroll
  for (int off = 32; off; off >>= 1) x += __shfl_xor(x, off, 64);
  return x;
}

// ---------- Kernel 1: QKV GEMM (tokens @ w_qkv^T) + split + RMSNorm ----------
// grid (40, 6): x = 64-col tile over 2560 rows of w_qkv, y = 64-row tile over 384 tokens
__global__ __launch_bounds__(256)
void qkv_norm_kernel(const float* __restrict__ tokens, const float* __restrict__ w_qkv,
                     const float* __restrict__ qw, const float* __restrict__ k1w,
                     const float* __restrict__ k2w, const float* __restrict__ v1w,
                     const float* __restrict__ v2w,
                     float* __restrict__ Q, float* __restrict__ K1, float* __restrict__ K2,
                     float* __restrict__ V1, float* __restrict__ V2)
{
  const int bn = blockIdx.x;   // 0..39
  const int bm = blockIdx.y;   // 0..5
  const int tid = threadIdx.x;
  const int tx = tid & 15, ty = tid >> 4;

  __shared__ float As[16][65];   // [k][m]
  __shared__ float Bs[16][65];   // [k][n]
  __shared__ float R[64][17];    // row sum-of-squares partials

  float acc[4][4] = {};

  for (int kt = 0; kt < DIM_; kt += 16) {
    #pragma unroll
    for (int c = 0; c < 4; ++c) {
      int e = tid + 256*c;
      int mm = e >> 4, kk = e & 15;
      As[kk][mm] = tokens[(bm*64 + mm)*DIM_ + kt + kk];
      Bs[kk][mm] = w_qkv[(bn*64 + mm)*DIM_ + kt + kk];
    }
    __syncthreads();
    #pragma unroll
    for (int kk = 0; kk < 16; ++kk) {
      float a[4], bb[4];
      #pragma unroll
      for (int i = 0; i < 4; ++i) a[i] = As[kk][ty*4 + i];
      #pragma unroll
      for (int j = 0; j < 4; ++j) bb[j] = Bs[kk][tx*4 + j];
      #pragma unroll
      for (int i = 0; i < 4; ++i)
        #pragma unroll
        for (int j = 0; j < 4; ++j)
          acc[i][j] = fmaf(a[i], bb[j], acc[i][j]);
    }
    __syncthreads();
  }

  // per-row (of this tile) sum of squares across the 64 cols = one RMSNorm group
  #pragma unroll
  for (int i = 0; i < 4; ++i) {
    float ss = acc[i][0]*acc[i][0] + acc[i][1]*acc[i][1]
             + acc[i][2]*acc[i][2] + acc[i][3]*acc[i][3];
    R[ty*4 + i][tx] = ss;
  }
  __syncthreads();

  // select destination array + norm weight from column-tile index
  const float* nw; float* dst; int hh;
  if (bn < 8)       { nw = qw; dst = Q; hh = bn; }
  else if (bn < 24) { int g = bn - 8;  hh = g >> 1; nw = (g & 1) ? k2w : k1w; dst = (g & 1) ? K2 : K1; }
  else              { int g = bn - 24; hh = g >> 1; nw = (g & 1) ? v2w : v1w; dst = (g & 1) ? V2 : V1; }

  #pragma unroll
  for (int i = 0; i < 4; ++i) {
    int row = ty*4 + i;
    int m = bm*64 + row;
    int b = (m >= N_) ? 1 : 0;
    int n = m - b*N_;
    float ss = 0.f;
    #pragma unroll
    for (int q = 0; q < 16; ++q) ss += R[row][q];
    float sc = rsqrtf(ss * (1.0f/64.0f) + EPS_RMS);
    size_t obase = (((size_t)(b*H_ + hh))*N_ + n)*DH_;
    #pragma unroll
    for (int j = 0; j < 4; ++j) {
      int d = tx*4 + j;
      dst[obase + d] = acc[i][j] * sc * nw[d];
    }
  }
}

// ---------- Kernel 2: streaming two-simplicial attention ----------
// grid 256: bid -> (itile 0..15, h 0..7, b 0..1); 256 threads = 4 waves x 3 query rows
__global__ __launch_bounds__(256)
void attn_kernel(const float* __restrict__ Qg, const float* __restrict__ K1g,
                 const float* __restrict__ K2g, const float* __restrict__ V1g,
                 const float* __restrict__ V2g, float* __restrict__ ATT)
{
  const int bid = blockIdx.x;
  const int itile = bid & 15;
  const int h = (bid >> 4) & 7;
  const int b = bid >> 7;
  const int tid = threadIdx.x;
  const int w = tid >> 6, lane = tid & 63;

  __shared__ unsigned int   K1s[192*33];   // packed bf16 pairs along d, ld=33 (conflict-free)
  __shared__ unsigned short V1h[192*64];   // bf16, [j][d]

  const size_t base = ((size_t)(b*H_ + h))*N_*DH_;

  // stage K1 (paired bf16) and V1 (bf16)
  for (int p = tid; p < 192*32; p += 256) {
    int j = p >> 5, d2 = p & 31;
    const float* src = K1g + base + j*64 + d2*2;
    unsigned int lo = f2bf(src[0]);
    unsigned int hi = f2bf(src[1]);
    K1s[j*33 + d2] = lo | (hi << 16);
  }
  for (int e = tid; e < 192*64; e += 256)
    V1h[e] = f2bf(V1g[base + e]);

  // this wave owns query rows i0..i0+2 ; lane <-> d
  const int i0 = itile*12 + w*3;
  float qs[3];
  #pragma unroll
  for (int c = 0; c < 3; ++c)
    qs[c] = Qg[base + (size_t)(i0 + c)*DH_ + lane] * SCALE_;

  __syncthreads();

  float mi[3] = {-INFINITY, -INFINITY, -INFINITY};
  float li[3] = {0.f, 0.f, 0.f};
  float o[3]  = {0.f, 0.f, 0.f};

  for (int k = 0; k < N_; ++k) {
    float k2v = K2g[base + (size_t)k*DH_ + lane];
    float v2v = V2g[base + (size_t)k*DH_ + lane];
    float qr[3];
    #pragma unroll
    for (int c = 0; c < 3; ++c) qr[c] = qs[c] * k2v;   // lane d holds q_d*k2[k,d]*scale

    // S phase: s[c][cc] = logits for (i0+c, j=lane+64*cc) at this k
    float s[3][3] = {};
    #pragma unroll 8
    for (int d2 = 0; d2 < 32; ++d2) {
      unsigned int u0 = K1s[lane*33 + d2];
      unsigned int u1 = K1s[(lane+64)*33 + d2];
      unsigned int u2 = K1s[(lane+128)*33 + d2];
      float ka[3] = {bf16_lo(u0), bf16_lo(u1), bf16_lo(u2)};
      float kb[3] = {bf16_hi(u0), bf16_hi(u1), bf16_hi(u2)};
      #pragma unroll
      for (int c = 0; c < 3; ++c) {
        float qa = rl(qr[c], 2*d2);
        float qb = rl(qr[c], 2*d2 + 1);
        #pragma unroll
        for (int cc = 0; cc < 3; ++cc) {
          s[c][cc] = fmaf(qa, ka[cc], s[c][cc]);
          s[c][cc] = fmaf(qb, kb[cc], s[c][cc]);
        }
      }
    }

    // online softmax over the 192 j's of this k (wave-private rows)
    float p[3][3];
    #pragma unroll
    for (int c = 0; c < 3; ++c) {
      float rm = waveMax(fmaxf(s[c][0], fmaxf(s[c][1], s[c][2])));
      float mn = fmaxf(mi[c], rm);
      float alpha = __expf(mi[c] - mn);       // first iter: exp(-inf)=0
      float p0 = __expf(s[c][0] - mn);
      float p1 = __expf(s[c][1] - mn);
      float p2 = __expf(s[c][2] - mn);
      float rs = waveSum(p0 + p1 + p2);
      li[c] = li[c]*alpha + rs;
      mi[c] = mn;
      o[c] *= alpha;
      p[c][0] = p0; p[c][1] = p1; p[c][2] = p2;
    }

    // T phase: t[c][d=lane] = sum_j p[c][j] * V1[j][lane]
    float t0 = 0.f, t1 = 0.f, t2 = 0.f;
    #pragma unroll
    for (int cc = 0; cc < 3; ++cc) {
      #pragma unroll 16
      for (int jl = 0; jl < 64; ++jl) {
        float v1f = __uint_as_float(((unsigned int)V1h[(cc*64 + jl)*64 + lane]) << 16);
        t0 = fmaf(rl(p[0][cc], jl), v1f, t0);
        t1 = fmaf(rl(p[1][cc], jl), v1f, t1);
        t2 = fmaf(rl(p[2][cc], jl), v1f, t2);
      }
    }
    o[0] = fmaf(t0, v2v, o[0]);
    o[1] = fmaf(t1, v2v, o[1]);
    o[2] = fmaf(t2, v2v, o[2]);
  }

  #pragma unroll
  for (int c = 0; c < 3; ++c) {
    float inv = 1.0f / li[c];
    int ig = i0 + c;
    ATT[((size_t)(b*N_) + ig)*(H_*DH_) + h*DH_ + lane] = o[c] * inv;
  }
}

// ---------- Kernel 3: output projection ATT @ w_out^T ----------
// grid (8, 6)
__global__ __launch_bounds__(256)
void out_proj_kernel(const float* __restrict__ ATT, const float* __restrict__ w_out,
                     float* __restrict__ out)
{
  const int bn = blockIdx.x;   // 0..7 over 512 cols
  const int bm = blockIdx.y;   // 0..5 over 384 rows
  const int tid = threadIdx.x;
  const int tx = tid & 15, ty = tid >> 4;

  __shared__ float As[16][65];
  __shared__ float Bs[16][65];

  float acc[4][4] = {};

  for (int kt = 0; kt < DIM_; kt += 16) {
    #pragma unroll
    for (int c = 0; c < 4; ++c) {
      int e = tid + 256*c;
      int mm = e >> 4, kk = e & 15;
      As[kk][mm] = ATT[(bm*64 + mm)*DIM_ + kt + kk];
      Bs[kk][mm] = w_out[(bn*64 + mm)*DIM_ + kt + kk];
    }
    __syncthreads();
    #pragma unroll
    for (int kk = 0; kk < 16; ++kk) {
      float a[4], bb[4];
      #pragma unroll
      for (int i = 0; i < 4; ++i) a[i] = As[kk][ty*4 + i];
      #pragma unroll
      for (int j = 0; j < 4; ++j) bb[j] = Bs[kk][tx*4 + j];
      #pragma unroll
      for (int i = 0; i < 4; ++i)
        #pragma unroll
        for (int j = 0; j < 4; ++j)
          acc[i][j] = fmaf(a[i], bb[j], acc[i][j]);
    }
    __syncthreads();
  }

  #pragma unroll
  for (int i = 0; i < 4; ++i) {
    int m = bm*64 + ty*4 + i;
    #pragma unroll
    for (int j = 0; j < 4; ++j)
      out[(size_t)m*DIM_ + bn*64 + tx*4 + j] = acc[i][j];
  }
}

// ---------- launch ----------
extern "C" void kernel_launch(void* const* d_in, const int* in_sizes, int n_in,
                              void* d_out, int out_size, void* d_ws, size_t ws_size,
                              hipStream_t stream) {
  const float* tokens = (const float*)d_in[0];
  const float* w_qkv  = (const float*)d_in[1];
  const float* w_out  = (const float*)d_in[2];
  const float* qw     = (const float*)d_in[3];
  const float* k1w    = (const float*)d_in[4];
  const float* k2w    = (const float*)d_in[5];
  const float* v1w    = (const float*)d_in[6];
  const float* v2w    = (const float*)d_in[7];
  float* out = (float*)d_out;

  float* ws  = (float*)d_ws;
  float* Q   = ws;
  float* K1  = ws + (size_t)ARR_;
  float* K2  = ws + (size_t)2*ARR_;
  float* V1  = ws + (size_t)3*ARR_;
  float* V2  = ws + (size_t)4*ARR_;
  float* ATT = ws + (size_t)5*ARR_;

  qkv_norm_kernel<<<dim3(40, 6), 256, 0, stream>>>(tokens, w_qkv, qw, k1w, k2w, v1w, v2w,
                                                   Q, K1, K2, V1, V2);
  attn_kernel<<<dim3(256), 256, 0, stream>>>(Q, K1, K2, V1, V2, ATT);
  out_proj_kernel<<<dim3(8, 6), 256, 0, stream>>>(ATT, w_out, out);
}

// Round 2
// 186.439 us; speedup vs baseline: 9.0307x; 9.0307x over previous
//
#include <hip/hip_runtime.h>

#define B_ 2
#define N_ 192
#define DIM_ 512
#define H_ 8
#define DH_ 64
#define EPS_RMS 1.1920929e-7f
#define SCALE_ 0.125f
#define ARR_ (B_*H_*N_*DH_)

typedef float v4f __attribute__((ext_vector_type(4)));
typedef short v8s __attribute__((ext_vector_type(8)));

// ---------- helpers ----------
__device__ __forceinline__ unsigned short f2bf(float f) {
  unsigned int u = __float_as_uint(f);
  return (unsigned short)((u + 0x7fffu + ((u >> 16) & 1u)) >> 16);  // RNE
}
__device__ __forceinline__ unsigned int pkbf(float a, float b) {
  unsigned int ua = __float_as_uint(a);
  ua = (ua + 0x7fffu + ((ua >> 16) & 1u)) >> 16;
  unsigned int ub = __float_as_uint(b);
  ub = (ub + 0x7fffu + ((ub >> 16) & 1u)) & 0xffff0000u;
  return ua | ub;
}
__device__ __forceinline__ float bf16_lo(unsigned int u) { return __uint_as_float(u << 16); }
__device__ __forceinline__ float bf16_hi(unsigned int u) { return __uint_as_float(u & 0xffff0000u); }

__device__ __forceinline__ v4f mfma16(uint4 a, uint4 b, v4f c) {
  union { uint4 u; v8s s; } ua, ub;
  ua.u = a; ub.u = b;
  return __builtin_amdgcn_mfma_f32_16x16x32_bf16(ua.s, ub.s, c, 0, 0, 0);
}

// ---------- Kernel 1: QKV GEMM + split + RMSNorm ----------
// grid (40, 12): x = 64-col tile over 2560 rows of w_qkv, y = 32-row tile over 384 tokens
__global__ __launch_bounds__(256)
void qkv_norm_kernel(const float* __restrict__ tokens, const float* __restrict__ w_qkv,
                     const float* __restrict__ qw, const float* __restrict__ k1w,
                     const float* __restrict__ k2w, const float* __restrict__ v1w,
                     const float* __restrict__ v2w,
                     float* __restrict__ Q, float* __restrict__ K1, float* __restrict__ K2,
                     float* __restrict__ V1, float* __restrict__ V2)
{
  const int bn = blockIdx.x;   // 0..39
  const int bm = blockIdx.y;   // 0..11
  const int tid = threadIdx.x;
  const int tx = tid & 15, ty = tid >> 4;

  __shared__ float As[16][33];
  __shared__ float Bs[16][65];
  __shared__ float R[32][17];

  float acc[2][4] = {};

  for (int kt = 0; kt < DIM_; kt += 16) {
    #pragma unroll
    for (int cc = 0; cc < 2; ++cc) {
      int e = tid + 256*cc;
      int mm = e >> 4, kk = e & 15;
      As[kk][mm] = tokens[(bm*32 + mm)*DIM_ + kt + kk];
    }
    #pragma unroll
    for (int cc = 0; cc < 4; ++cc) {
      int e = tid + 256*cc;
      int mm = e >> 4, kk = e & 15;
      Bs[kk][mm] = w_qkv[(bn*64 + mm)*DIM_ + kt + kk];
    }
    __syncthreads();
    #pragma unroll
    for (int kk = 0; kk < 16; ++kk) {
      float a0 = As[kk][ty*2], a1 = As[kk][ty*2 + 1];
      float b0 = Bs[kk][tx*4], b1 = Bs[kk][tx*4+1], b2 = Bs[kk][tx*4+2], b3 = Bs[kk][tx*4+3];
      acc[0][0] = fmaf(a0,b0,acc[0][0]); acc[0][1] = fmaf(a0,b1,acc[0][1]);
      acc[0][2] = fmaf(a0,b2,acc[0][2]); acc[0][3] = fmaf(a0,b3,acc[0][3]);
      acc[1][0] = fmaf(a1,b0,acc[1][0]); acc[1][1] = fmaf(a1,b1,acc[1][1]);
      acc[1][2] = fmaf(a1,b2,acc[1][2]); acc[1][3] = fmaf(a1,b3,acc[1][3]);
    }
    __syncthreads();
  }

  #pragma unroll
  for (int i = 0; i < 2; ++i) {
    float ss = acc[i][0]*acc[i][0] + acc[i][1]*acc[i][1]
             + acc[i][2]*acc[i][2] + acc[i][3]*acc[i][3];
    R[ty*2 + i][tx] = ss;
  }
  __syncthreads();

  const float* nw; float* dst; int hh;
  if (bn < 8)       { nw = qw; dst = Q; hh = bn; }
  else if (bn < 24) { int g = bn - 8;  hh = g >> 1; nw = (g & 1) ? k2w : k1w; dst = (g & 1) ? K2 : K1; }
  else              { int g = bn - 24; hh = g >> 1; nw = (g & 1) ? v2w : v1w; dst = (g & 1) ? V2 : V1; }

  #pragma unroll
  for (int i = 0; i < 2; ++i) {
    int row = ty*2 + i;
    int m = bm*32 + row;
    int b = (m >= N_) ? 1 : 0;
    int n = m - b*N_;
    float ss = 0.f;
    #pragma unroll
    for (int qq = 0; qq < 16; ++qq) ss += R[row][qq];
    float sc = rsqrtf(ss * (1.0f/64.0f) + EPS_RMS);
    size_t obase = (((size_t)(b*H_ + hh))*N_ + n)*DH_;
    #pragma unroll
    for (int j = 0; j < 4; ++j) {
      int d = tx*4 + j;
      dst[obase + d] = acc[i][j] * sc * nw[d];
    }
  }
}

// ---------- Kernel 2: per-query MFMA two-simplicial attention ----------
// grid 512: wg -> (bh = wg>>5, 6-query tile = (wg&31)*6). 4 waves, wave w owns j rows [48w,48w+48).
// Per i: S = (K1 .* q_i) @ K2^T (192x192x64), P = exp(S) (no max needed: logits O(10)),
// R = P @ V2 (192x64x192), out[d] = sum_j V1[j,d]*R[j,d] / sum(P).
// K2/V2 staged in LDS pre-packed in B-fragment order; K1/V1 in registers in A/D-frag order.
// P round-trip D->A layout through wave-private LDS (no barriers in main loop).
__global__ __launch_bounds__(256, 2)
void attn_kernel(const float* __restrict__ Qg, const float* __restrict__ K1g,
                 const float* __restrict__ K2g, const float* __restrict__ V1g,
                 const float* __restrict__ V2g, float* __restrict__ ATT)
{
  __shared__ __align__(16) unsigned char lds[64032];
  // layout: K2B @0 (24576) | V2B @24576 (24576) | P @49152 (4x3072) | qS @61440 (1536)
  //         | redF @62976 (1024) | redL @64000 (16)
  uint4* K2B  = (uint4*)(lds);
  uint4* V2B  = (uint4*)(lds + 24576);
  float* qS   = (float*)(lds + 61440);
  float* redF = (float*)(lds + 62976);
  float* redL = (float*)(lds + 64000);

  const int tid = threadIdx.x;
  const int w = tid >> 6, l = tid & 63;
  const int c = l & 15, q = l >> 4;
  const int bh = blockIdx.x >> 5;
  const int sub = blockIdx.x & 31;
  const int b = bh >> 3, h = bh & 7;
  const int i0 = sub * 6;
  const size_t base = (size_t)bh * (N_ * DH_);

  // ---- stage K2 in B-frag-packed order: block (nt 0..11, ks 0..1), lane ll:
  //      n=kcol=nt*16+(ll&15), k=d=ks*32+(ll>>4)*8 + 0..7
  for (int t = tid; t < 24*64; t += 256) {
    int blk = t >> 6, ll = t & 63;
    int nt = blk >> 1, ks = blk & 1;
    int kcol = nt*16 + (ll & 15);
    int d0 = ks*32 + ((ll >> 4) << 3);
    const float* s = K2g + base + kcol*64 + d0;
    float4 f0 = *(const float4*)s;
    float4 f1 = *(const float4*)(s + 4);
    uint4 wv;
    wv.x = pkbf(f0.x, f0.y); wv.y = pkbf(f0.z, f0.w);
    wv.z = pkbf(f1.x, f1.y); wv.w = pkbf(f1.z, f1.w);
    K2B[t] = wv;
  }
  // ---- stage V2 in B-frag-packed order: block (nt(d) 0..3, ks(kcol) 0..5):
  //      n=d=nt*16+(ll&15), k=kcol=ks*32+(ll>>4)*8 + 0..7
  for (int t = tid; t < 24*64; t += 256) {
    int blk = t >> 6, ll = t & 63;
    int nt = blk / 6, ks = blk % 6;
    int d = nt*16 + (ll & 15);
    int kc0 = ks*32 + ((ll >> 4) << 3);
    const float* s = V2g + base + kc0*64 + d;
    uint4 wv;
    wv.x = pkbf(s[0],   s[64]);
    wv.y = pkbf(s[128], s[192]);
    wv.z = pkbf(s[256], s[320]);
    wv.w = pkbf(s[384], s[448]);
    V2B[t] = wv;
  }
  // ---- stage q (pre-scaled)
  for (int t = tid; t < 6*64; t += 256)
    qS[t] = Qg[base + (size_t)(i0 + (t >> 6))*64 + (t & 63)] * SCALE_;

  // ---- K1 rows in registers, A-frag order: (jt 0..2, ks 0..1):
  //      m=c -> j=w*48+jt*16+c ; k=d=ks*32+q*8 + 0..7 (bf16 pairs)
  unsigned int k1p[6][4];
  #pragma unroll
  for (int jt = 0; jt < 3; ++jt)
    #pragma unroll
    for (int ks = 0; ks < 2; ++ks) {
      int j = w*48 + jt*16 + c;
      int d0 = ks*32 + (q << 3);
      const float* s = K1g + base + j*64 + d0;
      float4 f0 = *(const float4*)s;
      float4 f1 = *(const float4*)(s + 4);
      k1p[jt*2+ks][0] = pkbf(f0.x, f0.y);
      k1p[jt*2+ks][1] = pkbf(f0.z, f0.w);
      k1p[jt*2+ks][2] = pkbf(f1.x, f1.y);
      k1p[jt*2+ks][3] = pkbf(f1.z, f1.w);
    }
  // ---- V1 in registers, D-layout order: (jt 0..2, dt 0..3), rows r=q*4+0..3, col d=dt*16+c
  unsigned int v1p[12][2];
  #pragma unroll
  for (int jt = 0; jt < 3; ++jt)
    #pragma unroll
    for (int dt = 0; dt < 4; ++dt) {
      int jb = w*48 + jt*16 + q*4;
      int d = dt*16 + c;
      const float* s = V1g + base + jb*64 + d;
      v1p[jt*4+dt][0] = pkbf(s[0],   s[64]);
      v1p[jt*4+dt][1] = pkbf(s[128], s[192]);
    }

  __syncthreads();

  unsigned char* Pw = lds + 49152 + w*3072;     // wave-private: 3 blocks x 1KB (jt)
  const int rs = l ^ (l >> 4);                  // read-slot (XOR bank swizzle)

  for (int ii = 0; ii < 6; ++ii) {
    // q fragment values for this i
    float qv[2][8];
    #pragma unroll
    for (int ks = 0; ks < 2; ++ks) {
      const float* s = qS + ii*64 + ks*32 + (q << 3);
      float4 a = *(const float4*)s;
      float4 bq = *(const float4*)(s + 4);
      qv[ks][0]=a.x; qv[ks][1]=a.y; qv[ks][2]=a.z; qv[ks][3]=a.w;
      qv[ks][4]=bq.x; qv[ks][5]=bq.y; qv[ks][6]=bq.z; qv[ks][7]=bq.w;
    }
    // A-frags: (K1 .* q_scaled) -> bf16
    uint4 afr[3][2];
    #pragma unroll
    for (int jt = 0; jt < 3; ++jt)
      #pragma unroll
      for (int ks = 0; ks < 2; ++ks) {
        unsigned int wds[4];
        #pragma unroll
        for (int e = 0; e < 4; ++e) {
          float lo = bf16_lo(k1p[jt*2+ks][e]) * qv[ks][2*e];
          float hi = bf16_hi(k1p[jt*2+ks][e]) * qv[ks][2*e+1];
          wds[e] = pkbf(lo, hi);
        }
        afr[jt][ks].x = wds[0]; afr[jt][ks].y = wds[1];
        afr[jt][ks].z = wds[2]; afr[jt][ks].w = wds[3];
      }

    v4f racc[3][4];
    #pragma unroll
    for (int jt = 0; jt < 3; ++jt)
      #pragma unroll
      for (int dt = 0; dt < 4; ++dt)
        racc[jt][dt] = (v4f){0.f, 0.f, 0.f, 0.f};
    float psum = 0.f;

    for (int ch = 0; ch < 6; ++ch) {
      // S chunk: cols kcol in [ch*32, ch*32+32)
      uint4 kb[2][2];
      #pragma unroll
      for (int ktl = 0; ktl < 2; ++ktl)
        #pragma unroll
        for (int ks = 0; ks < 2; ++ks)
          kb[ktl][ks] = K2B[((ch*2 + ktl)*2 + ks)*64 + l];

      v4f sacc[3][2];
      #pragma unroll
      for (int jt = 0; jt < 3; ++jt)
        #pragma unroll
        for (int ktl = 0; ktl < 2; ++ktl) {
          v4f z = (v4f){0.f, 0.f, 0.f, 0.f};
          z = mfma16(afr[jt][0], kb[ktl][0], z);
          z = mfma16(afr[jt][1], kb[ktl][1], z);
          sacc[jt][ktl] = z;
        }

      // exp (no max: logits are O(10) for RMS-normalized inputs), write P in A-frag layout
      #pragma unroll
      for (int jt = 0; jt < 3; ++jt)
        #pragma unroll
        for (int ktl = 0; ktl < 2; ++ktl) {
          int kc = ktl*16 + c;          // col within 32-chunk
          int kc3 = kc >> 3;
          #pragma unroll
          for (int r = 0; r < 4; ++r) {
            float p = __expf(sacc[jt][ktl][r]);
            psum += p;
            int slot = kc3*16 + q*4 + r;
            slot ^= (slot >> 4);        // bank swizzle (8-way -> 4-way)
            *(unsigned short*)(Pw + jt*1024 + slot*16 + ((kc & 7) << 1)) = f2bf(p);
          }
        }

      // R += P_chunk @ V2_chunk  (wave-private LDS, DS pipe is in-order per wave)
      uint4 pa[3];
      #pragma unroll
      for (int jt = 0; jt < 3; ++jt)
        pa[jt] = *(uint4*)(Pw + jt*1024 + rs*16);
      uint4 vb[4];
      #pragma unroll
      for (int dt = 0; dt < 4; ++dt)
        vb[dt] = V2B[(dt*6 + ch)*64 + l];
      #pragma unroll
      for (int jt = 0; jt < 3; ++jt)
        #pragma unroll
        for (int dt = 0; dt < 4; ++dt)
          racc[jt][dt] = mfma16(pa[jt], vb[dt], racc[jt][dt]);
    }

    // wave-reduce softmax denominator
    float lsum = psum;
    #pragma unroll
    for (int off = 32; off; off >>= 1) lsum += __shfl_xor(lsum, off, 64);

    // out partials: op[dt] = sum over this wave's j of V1[j,d]*R[j,d], d = dt*16+c
    float op[4] = {0.f, 0.f, 0.f, 0.f};
    #pragma unroll
    for (int jt = 0; jt < 3; ++jt)
      #pragma unroll
      for (int dt = 0; dt < 4; ++dt) {
        op[dt] = fmaf(bf16_lo(v1p[jt*4+dt][0]), racc[jt][dt][0], op[dt]);
        op[dt] = fmaf(bf16_hi(v1p[jt*4+dt][0]), racc[jt][dt][1], op[dt]);
        op[dt] = fmaf(bf16_lo(v1p[jt*4+dt][1]), racc[jt][dt][2], op[dt]);
        op[dt] = fmaf(bf16_hi(v1p[jt*4+dt][1]), racc[jt][dt][3], op[dt]);
      }
    #pragma unroll
    for (int dt = 0; dt < 4; ++dt) {
      op[dt] += __shfl_xor(op[dt], 16, 64);
      op[dt] += __shfl_xor(op[dt], 32, 64);
    }
    if (l < 16) {
      #pragma unroll
      for (int dt = 0; dt < 4; ++dt) redF[w*64 + dt*16 + l] = op[dt];
    }
    if (l == 0) redL[w] = lsum;
    __syncthreads();
    if (tid < 64) {
      float o = redF[tid] + redF[64 + tid] + redF[128 + tid] + redF[192 + tid];
      float lt = redL[0] + redL[1] + redL[2] + redL[3];
      ATT[((size_t)(b*N_ + i0 + ii))*(H_*DH_) + h*64 + tid] = o / lt;
    }
    __syncthreads();
  }
}

// ---------- Kernel 3: output projection ATT @ w_out^T ----------
// grid (16, 12): 32x32 tiles
__global__ __launch_bounds__(256)
void out_proj_kernel(const float* __restrict__ ATT, const float* __restrict__ w_out,
                     float* __restrict__ out)
{
  const int bn = blockIdx.x;   // 0..15
  const int bm = blockIdx.y;   // 0..11
  const int tid = threadIdx.x;
  const int tx = tid & 15, ty = tid >> 4;

  __shared__ float As[16][33];
  __shared__ float Bs[16][33];

  float acc[2][2] = {};

  for (int kt = 0; kt < DIM_; kt += 16) {
    #pragma unroll
    for (int cc = 0; cc < 2; ++cc) {
      int e = tid + 256*cc;
      int mm = e >> 4, kk = e & 15;
      As[kk][mm] = ATT[(bm*32 + mm)*DIM_ + kt + kk];
      Bs[kk][mm] = w_out[(bn*32 + mm)*DIM_ + kt + kk];
    }
    __syncthreads();
    #pragma unroll
    for (int kk = 0; kk < 16; ++kk) {
      float a0 = As[kk][ty*2], a1 = As[kk][ty*2 + 1];
      float b0 = Bs[kk][tx*2], b1 = Bs[kk][tx*2 + 1];
      acc[0][0] = fmaf(a0,b0,acc[0][0]); acc[0][1] = fmaf(a0,b1,acc[0][1]);
      acc[1][0] = fmaf(a1,b0,acc[1][0]); acc[1][1] = fmaf(a1,b1,acc[1][1]);
    }
    __syncthreads();
  }

  #pragma unroll
  for (int i = 0; i < 2; ++i)
    #pragma unroll
    for (int j = 0; j < 2; ++j)
      out[(size_t)(bm*32 + ty*2 + i)*DIM_ + bn*32 + tx*2 + j] = acc[i][j];
}

// ---------- launch ----------
extern "C" void kernel_launch(void* const* d_in, const int* in_sizes, int n_in,
                              void* d_out, int out_size, void* d_ws, size_t ws_size,
                              hipStream_t stream) {
  const float* tokens = (const float*)d_in[0];
  const float* w_qkv  = (const float*)d_in[1];
  const float* w_out  = (const float*)d_in[2];
  const float* qw     = (const float*)d_in[3];
  const float* k1w    = (const float*)d_in[4];
  const float* k2w    = (const float*)d_in[5];
  const float* v1w    = (const float*)d_in[6];
  const float* v2w    = (const float*)d_in[7];
  float* out = (float*)d_out;

  float* ws  = (float*)d_ws;
  float* Q   = ws;
  float* K1  = ws + (size_t)ARR_;
  float* K2  = ws + (size_t)2*ARR_;
  float* V1  = ws + (size_t)3*ARR_;
  float* V2  = ws + (size_t)4*ARR_;
  float* ATT = ws + (size_t)5*ARR_;

  qkv_norm_kernel<<<dim3(40, 12), 256, 0, stream>>>(tokens, w_qkv, qw, k1w, k2w, v1w, v2w,
                                                    Q, K1, K2, V1, V2);
  attn_kernel<<<dim3(512), 256, 0, stream>>>(Q, K1, K2, V1, V2, ATT);
  out_proj_kernel<<<dim3(16, 12), 256, 0, stream>>>(ATT, w_out, out);
}

// Round 3
// 139.482 us; speedup vs baseline: 12.0709x; 1.3367x over previous
//
#include <hip/hip_runtime.h>

#define B_ 2
#define N_ 192
#define DIM_ 512
#define H_ 8
#define DH_ 64
#define EPS_RMS 1.1920929e-7f
#define QSC 0.18033688011112042f   // 0.125 * log2(e)  (logits in base-2)
#define ARR_ (B_*H_*N_*DH_)

typedef float v4f __attribute__((ext_vector_type(4)));
typedef short v8s __attribute__((ext_vector_type(8)));

// ---------- helpers ----------
// HW packed fp32->bf16 (1 instr): dst.lo = bf16(a), dst.hi = bf16(b)
__device__ __forceinline__ unsigned int cvtpk(float a, float b) {
  unsigned int d;
  asm("v_cvt_pk_bf16_f32 %0, %1, %2" : "=v"(d) : "v"(a), "v"(b));
  return d;
}
__device__ __forceinline__ float bf16_lo(unsigned int u) { return __uint_as_float(u << 16); }
__device__ __forceinline__ float bf16_hi(unsigned int u) { return __uint_as_float(u & 0xffff0000u); }

#if __has_builtin(__builtin_amdgcn_exp2f)
__device__ __forceinline__ float fexp2(float x) { return __builtin_amdgcn_exp2f(x); }
#else
__device__ __forceinline__ float fexp2(float x) {
  float r; asm("v_exp_f32 %0, %1" : "=v"(r) : "v"(x)); return r;
}
#endif

__device__ __forceinline__ v4f mfma16(uint4 a, uint4 b, v4f c) {
  union { uint4 u; v8s s; } ua, ub;
  ua.u = a; ub.u = b;
  return __builtin_amdgcn_mfma_f32_16x16x32_bf16(ua.s, ub.s, c, 0, 0, 0);
}

// split one 8-float group into hi/lo bf16 fragments (16B each)
__device__ __forceinline__ void split8(const float* s, uint4& hi, uint4& lo) {
  float4 f0 = *(const float4*)s;
  float4 f1 = *(const float4*)(s + 4);
  hi.x = cvtpk(f0.x, f0.y); hi.y = cvtpk(f0.z, f0.w);
  hi.z = cvtpk(f1.x, f1.y); hi.w = cvtpk(f1.z, f1.w);
  lo.x = cvtpk(f0.x - bf16_lo(hi.x), f0.y - bf16_hi(hi.x));
  lo.y = cvtpk(f0.z - bf16_lo(hi.y), f0.w - bf16_hi(hi.y));
  lo.z = cvtpk(f1.x - bf16_lo(hi.z), f1.y - bf16_hi(hi.z));
  lo.w = cvtpk(f1.z - bf16_lo(hi.w), f1.w - bf16_hi(hi.w));
}

// ---------- Kernel 1: QKV GEMM (split-bf16 MFMA) + split + RMSNorm ----------
// grid (40, 12): bn = 64-row group of w_qkv (one (dst,head) norm group), bm = 32 token rows.
// 4 waves: w -> (mhalf = w&1: 16 token rows, nhalf = w>>1: 32 cols).
// C = A.B^T via 3 mfma passes: Ahi.Bhi + Ahi.Blo + Alo.Bhi (rel err ~1e-5).
__global__ __launch_bounds__(256, 2)
void qkv_mfma_kernel(const float* __restrict__ tokens, const float* __restrict__ w_qkv,
                     const float* __restrict__ qw, const float* __restrict__ k1w,
                     const float* __restrict__ k2w, const float* __restrict__ v1w,
                     const float* __restrict__ v2w,
                     float* __restrict__ Q, float* __restrict__ K1, float* __restrict__ K2,
                     float* __restrict__ V1, float* __restrict__ V2)
{
  const int bn = blockIdx.x;   // 0..39
  const int bm = blockIdx.y;   // 0..11
  const int tid = threadIdx.x;
  const int w = tid >> 6, l = tid & 63;
  const int c = l & 15, q = l >> 4;
  const int mhalf = w & 1, nhalf = w >> 1;

  __shared__ __align__(16) uint4 Ahi[8*32], Alo[8*32];   // [g][m^g], 4KB each
  __shared__ __align__(16) uint4 Bhi[8*64], Blo[8*64];   // [g][n^g], 8KB each
  __shared__ float red[32][2];

  v4f acc[2] = {(v4f){0,0,0,0}, (v4f){0,0,0,0}};

  for (int kc = 0; kc < 8; ++kc) {
    const int k0 = kc * 64;
    // stage A: thread t -> row m=t>>3, k-group g=t&7 (8 consecutive k)
    {
      int m = tid >> 3, g = tid & 7;
      uint4 hi, lo;
      split8(tokens + (size_t)(bm*32 + m)*DIM_ + k0 + g*8, hi, lo);
      Ahi[g*32 + (m ^ g)] = hi;
      Alo[g*32 + (m ^ g)] = lo;
    }
    // stage B: 512 groups, 2 per thread
    #pragma unroll
    for (int cc = 0; cc < 2; ++cc) {
      int e = tid + 256*cc;
      int n = e >> 3, g = e & 7;
      uint4 hi, lo;
      split8(w_qkv + (size_t)(bn*64 + n)*DIM_ + k0 + g*8, hi, lo);
      Bhi[g*64 + (n ^ g)] = hi;
      Blo[g*64 + (n ^ g)] = lo;
    }
    __syncthreads();
    #pragma unroll
    for (int kh = 0; kh < 2; ++kh) {
      int g = kh*4 + q;
      int m = mhalf*16 + c;
      uint4 ah = Ahi[g*32 + (m ^ g)];
      uint4 al = Alo[g*32 + (m ^ g)];
      #pragma unroll
      for (int nt = 0; nt < 2; ++nt) {
        int n = nhalf*32 + nt*16 + c;
        uint4 bh = Bhi[g*64 + (n ^ g)];
        uint4 bl = Blo[g*64 + (n ^ g)];
        acc[nt] = mfma16(ah, bh, acc[nt]);
        acc[nt] = mfma16(ah, bl, acc[nt]);
        acc[nt] = mfma16(al, bh, acc[nt]);
      }
    }
    __syncthreads();
  }

  // ---- RMSNorm epilogue. D-layout: col = nt*16+c (within nhalf), row = q*4+r.
  float ss[4];
  #pragma unroll
  for (int r = 0; r < 4; ++r) {
    ss[r] = acc[0][r]*acc[0][r] + acc[1][r]*acc[1][r];
    #pragma unroll
    for (int off = 1; off < 16; off <<= 1) ss[r] += __shfl_xor(ss[r], off, 64);
  }
  if (c == 0) {
    #pragma unroll
    for (int r = 0; r < 4; ++r) red[mhalf*16 + q*4 + r][nhalf] = ss[r];
  }
  __syncthreads();

  const float* nw; float* dst; int hh;
  if (bn < 8)       { nw = qw; dst = Q; hh = bn; }
  else if (bn < 24) { int g = bn - 8;  hh = g >> 1; nw = (g & 1) ? k2w : k1w; dst = (g & 1) ? K2 : K1; }
  else              { int g = bn - 24; hh = g >> 1; nw = (g & 1) ? v2w : v1w; dst = (g & 1) ? V2 : V1; }

  #pragma unroll
  for (int r = 0; r < 4; ++r) {
    int row = mhalf*16 + q*4 + r;
    float sst = red[row][0] + red[row][1];
    float sc = rsqrtf(sst * (1.0f/64.0f) + EPS_RMS);
    int m = bm*32 + row;
    int b = (m >= N_) ? 1 : 0;
    int n = m - b*N_;
    size_t obase = (((size_t)(b*H_ + hh))*N_ + n)*DH_;
    #pragma unroll
    for (int nt = 0; nt < 2; ++nt) {
      int d = nhalf*32 + nt*16 + c;
      dst[obase + d] = acc[nt][r] * sc * nw[d];
    }
  }
}

// ---------- Kernel 2: per-query MFMA two-simplicial attention ----------
__global__ __launch_bounds__(256, 2)
void attn_kernel(const float* __restrict__ Qg, const float* __restrict__ K1g,
                 const float* __restrict__ K2g, const float* __restrict__ V1g,
                 const float* __restrict__ V2g, float* __restrict__ ATT)
{
  __shared__ __align__(16) unsigned char lds[64032];
  uint4* K2B  = (uint4*)(lds);
  uint4* V2B  = (uint4*)(lds + 24576);
  float* qS   = (float*)(lds + 61440);
  float* redF = (float*)(lds + 62976);
  float* redL = (float*)(lds + 64000);

  const int tid = threadIdx.x;
  const int w = tid >> 6, l = tid & 63;
  const int c = l & 15, q = l >> 4;
  const int bh = blockIdx.x >> 5;
  const int sub = blockIdx.x & 31;
  const int b = bh >> 3, h = bh & 7;
  const int i0 = sub * 6;
  const size_t base = (size_t)bh * (N_ * DH_);

  for (int t = tid; t < 24*64; t += 256) {
    int blk = t >> 6, ll = t & 63;
    int nt = blk >> 1, ks = blk & 1;
    int kcol = nt*16 + (ll & 15);
    int d0 = ks*32 + ((ll >> 4) << 3);
    const float* s = K2g + base + kcol*64 + d0;
    float4 f0 = *(const float4*)s;
    float4 f1 = *(const float4*)(s + 4);
    uint4 wv;
    wv.x = cvtpk(f0.x, f0.y); wv.y = cvtpk(f0.z, f0.w);
    wv.z = cvtpk(f1.x, f1.y); wv.w = cvtpk(f1.z, f1.w);
    K2B[t] = wv;
  }
  for (int t = tid; t < 24*64; t += 256) {
    int blk = t >> 6, ll = t & 63;
    int nt = blk / 6, ks = blk % 6;
    int d = nt*16 + (ll & 15);
    int kc0 = ks*32 + ((ll >> 4) << 3);
    const float* s = V2g + base + kc0*64 + d;
    uint4 wv;
    wv.x = cvtpk(s[0],   s[64]);
    wv.y = cvtpk(s[128], s[192]);
    wv.z = cvtpk(s[256], s[320]);
    wv.w = cvtpk(s[384], s[448]);
    V2B[t] = wv;
  }
  for (int t = tid; t < 6*64; t += 256)
    qS[t] = Qg[base + (size_t)(i0 + (t >> 6))*64 + (t & 63)] * QSC;

  unsigned int k1p[6][4];
  #pragma unroll
  for (int jt = 0; jt < 3; ++jt)
    #pragma unroll
    for (int ks = 0; ks < 2; ++ks) {
      int j = w*48 + jt*16 + c;
      int d0 = ks*32 + (q << 3);
      const float* s = K1g + base + j*64 + d0;
      float4 f0 = *(const float4*)s;
      float4 f1 = *(const float4*)(s + 4);
      k1p[jt*2+ks][0] = cvtpk(f0.x, f0.y);
      k1p[jt*2+ks][1] = cvtpk(f0.z, f0.w);
      k1p[jt*2+ks][2] = cvtpk(f1.x, f1.y);
      k1p[jt*2+ks][3] = cvtpk(f1.z, f1.w);
    }
  unsigned int v1p[12][2];
  #pragma unroll
  for (int jt = 0; jt < 3; ++jt)
    #pragma unroll
    for (int dt = 0; dt < 4; ++dt) {
      int jb = w*48 + jt*16 + q*4;
      int d = dt*16 + c;
      const float* s = V1g + base + jb*64 + d;
      v1p[jt*4+dt][0] = cvtpk(s[0],   s[64]);
      v1p[jt*4+dt][1] = cvtpk(s[128], s[192]);
    }

  __syncthreads();

  unsigned char* Pw = lds + 49152 + w*3072;
  const int rs = l ^ (l >> 4);

  for (int ii = 0; ii < 6; ++ii) {
    float qv[2][8];
    #pragma unroll
    for (int ks = 0; ks < 2; ++ks) {
      const float* s = qS + ii*64 + ks*32 + (q << 3);
      float4 a = *(const float4*)s;
      float4 bq = *(const float4*)(s + 4);
      qv[ks][0]=a.x; qv[ks][1]=a.y; qv[ks][2]=a.z; qv[ks][3]=a.w;
      qv[ks][4]=bq.x; qv[ks][5]=bq.y; qv[ks][6]=bq.z; qv[ks][7]=bq.w;
    }
    uint4 afr[3][2];
    #pragma unroll
    for (int jt = 0; jt < 3; ++jt)
      #pragma unroll
      for (int ks = 0; ks < 2; ++ks) {
        unsigned int wds[4];
        #pragma unroll
        for (int e = 0; e < 4; ++e) {
          float lo = bf16_lo(k1p[jt*2+ks][e]) * qv[ks][2*e];
          float hi = bf16_hi(k1p[jt*2+ks][e]) * qv[ks][2*e+1];
          wds[e] = cvtpk(lo, hi);
        }
        afr[jt][ks].x = wds[0]; afr[jt][ks].y = wds[1];
        afr[jt][ks].z = wds[2]; afr[jt][ks].w = wds[3];
      }

    v4f racc[3][4];
    #pragma unroll
    for (int jt = 0; jt < 3; ++jt)
      #pragma unroll
      for (int dt = 0; dt < 4; ++dt)
        racc[jt][dt] = (v4f){0.f, 0.f, 0.f, 0.f};
    float psum = 0.f;

    for (int ch = 0; ch < 6; ++ch) {
      uint4 kb[2][2];
      #pragma unroll
      for (int ktl = 0; ktl < 2; ++ktl)
        #pragma unroll
        for (int ks = 0; ks < 2; ++ks)
          kb[ktl][ks] = K2B[((ch*2 + ktl)*2 + ks)*64 + l];

      v4f sacc[3][2];
      #pragma unroll
      for (int jt = 0; jt < 3; ++jt)
        #pragma unroll
        for (int ktl = 0; ktl < 2; ++ktl) {
          v4f z = (v4f){0.f, 0.f, 0.f, 0.f};
          z = mfma16(afr[jt][0], kb[ktl][0], z);
          z = mfma16(afr[jt][1], kb[ktl][1], z);
          sacc[jt][ktl] = z;
        }

      // exp2 of base-2 logits; write P in A-frag layout (wave-private LDS)
      #pragma unroll
      for (int jt = 0; jt < 3; ++jt)
        #pragma unroll
        for (int ktl = 0; ktl < 2; ++ktl) {
          int kc = ktl*16 + c;
          int kc3 = kc >> 3;
          #pragma unroll
          for (int r = 0; r < 4; ++r) {
            float p = fexp2(sacc[jt][ktl][r]);
            psum += p;
            int slot = kc3*16 + q*4 + r;
            slot ^= (slot >> 4);
            *(unsigned short*)(Pw + jt*1024 + slot*16 + ((kc & 7) << 1)) =
                (unsigned short)cvtpk(p, p);
          }
        }

      uint4 pa[3];
      #pragma unroll
      for (int jt = 0; jt < 3; ++jt)
        pa[jt] = *(uint4*)(Pw + jt*1024 + rs*16);
      uint4 vb[4];
      #pragma unroll
      for (int dt = 0; dt < 4; ++dt)
        vb[dt] = V2B[(dt*6 + ch)*64 + l];
      #pragma unroll
      for (int jt = 0; jt < 3; ++jt)
        #pragma unroll
        for (int dt = 0; dt < 4; ++dt)
          racc[jt][dt] = mfma16(pa[jt], vb[dt], racc[jt][dt]);
    }

    float lsum = psum;
    #pragma unroll
    for (int off = 32; off; off >>= 1) lsum += __shfl_xor(lsum, off, 64);

    float op[4] = {0.f, 0.f, 0.f, 0.f};
    #pragma unroll
    for (int jt = 0; jt < 3; ++jt)
      #pragma unroll
      for (int dt = 0; dt < 4; ++dt) {
        op[dt] = fmaf(bf16_lo(v1p[jt*4+dt][0]), racc[jt][dt][0], op[dt]);
        op[dt] = fmaf(bf16_hi(v1p[jt*4+dt][0]), racc[jt][dt][1], op[dt]);
        op[dt] = fmaf(bf16_lo(v1p[jt*4+dt][1]), racc[jt][dt][2], op[dt]);
        op[dt] = fmaf(bf16_hi(v1p[jt*4+dt][1]), racc[jt][dt][3], op[dt]);
      }
    #pragma unroll
    for (int dt = 0; dt < 4; ++dt) {
      op[dt] += __shfl_xor(op[dt], 16, 64);
      op[dt] += __shfl_xor(op[dt], 32, 64);
    }
    if (l < 16) {
      #pragma unroll
      for (int dt = 0; dt < 4; ++dt) redF[w*64 + dt*16 + l] = op[dt];
    }
    if (l == 0) redL[w] = lsum;
    __syncthreads();
    if (tid < 64) {
      float o = redF[tid] + redF[64 + tid] + redF[128 + tid] + redF[192 + tid];
      float lt = redL[0] + redL[1] + redL[2] + redL[3];
      ATT[((size_t)(b*N_ + i0 + ii))*(H_*DH_) + h*64 + tid] = o / lt;
    }
    __syncthreads();
  }
}

// ---------- Kernel 3: output projection (split-bf16 MFMA) ----------
// grid (8, 12): bn = 64 cols of w_out rows, bm = 32 rows of ATT
__global__ __launch_bounds__(256, 2)
void out_proj_kernel(const float* __restrict__ ATT, const float* __restrict__ w_out,
                     float* __restrict__ out)
{
  const int bn = blockIdx.x;   // 0..7
  const int bm = blockIdx.y;   // 0..11
  const int tid = threadIdx.x;
  const int w = tid >> 6, l = tid & 63;
  const int c = l & 15, q = l >> 4;
  const int mhalf = w & 1, nhalf = w >> 1;

  __shared__ __align__(16) uint4 Ahi[8*32], Alo[8*32];
  __shared__ __align__(16) uint4 Bhi[8*64], Blo[8*64];

  v4f acc[2] = {(v4f){0,0,0,0}, (v4f){0,0,0,0}};

  for (int kc = 0; kc < 8; ++kc) {
    const int k0 = kc * 64;
    {
      int m = tid >> 3, g = tid & 7;
      uint4 hi, lo;
      split8(ATT + (size_t)(bm*32 + m)*DIM_ + k0 + g*8, hi, lo);
      Ahi[g*32 + (m ^ g)] = hi;
      Alo[g*32 + (m ^ g)] = lo;
    }
    #pragma unroll
    for (int cc = 0; cc < 2; ++cc) {
      int e = tid + 256*cc;
      int n = e >> 3, g = e & 7;
      uint4 hi, lo;
      split8(w_out + (size_t)(bn*64 + n)*DIM_ + k0 + g*8, hi, lo);
      Bhi[g*64 + (n ^ g)] = hi;
      Blo[g*64 + (n ^ g)] = lo;
    }
    __syncthreads();
    #pragma unroll
    for (int kh = 0; kh < 2; ++kh) {
      int g = kh*4 + q;
      int m = mhalf*16 + c;
      uint4 ah = Ahi[g*32 + (m ^ g)];
      uint4 al = Alo[g*32 + (m ^ g)];
      #pragma unroll
      for (int nt = 0; nt < 2; ++nt) {
        int n = nhalf*32 + nt*16 + c;
        uint4 bh = Bhi[g*64 + (n ^ g)];
        uint4 bl = Blo[g*64 + (n ^ g)];
        acc[nt] = mfma16(ah, bh, acc[nt]);
        acc[nt] = mfma16(ah, bl, acc[nt]);
        acc[nt] = mfma16(al, bh, acc[nt]);
      }
    }
    __syncthreads();
  }

  #pragma unroll
  for (int r = 0; r < 4; ++r) {
    int m = bm*32 + mhalf*16 + q*4 + r;
    #pragma unroll
    for (int nt = 0; nt < 2; ++nt) {
      int d = nhalf*32 + nt*16 + c;
      out[(size_t)m*DIM_ + bn*64 + d] = acc[nt][r];
    }
  }
}

// ---------- launch ----------
extern "C" void kernel_launch(void* const* d_in, const int* in_sizes, int n_in,
                              void* d_out, int out_size, void* d_ws, size_t ws_size,
                              hipStream_t stream) {
  const float* tokens = (const float*)d_in[0];
  const float* w_qkv  = (const float*)d_in[1];
  const float* w_out  = (const float*)d_in[2];
  const float* qw     = (const float*)d_in[3];
  const float* k1w    = (const float*)d_in[4];
  const float* k2w    = (const float*)d_in[5];
  const float* v1w    = (const float*)d_in[6];
  const float* v2w    = (const float*)d_in[7];
  float* out = (float*)d_out;

  float* ws  = (float*)d_ws;
  float* Q   = ws;
  float* K1  = ws + (size_t)ARR_;
  float* K2  = ws + (size_t)2*ARR_;
  float* V1  = ws + (size_t)3*ARR_;
  float* V2  = ws + (size_t)4*ARR_;
  float* ATT = ws + (size_t)5*ARR_;

  qkv_mfma_kernel<<<dim3(40, 12), 256, 0, stream>>>(tokens, w_qkv, qw, k1w, k2w, v1w, v2w,
                                                    Q, K1, K2, V1, V2);
  attn_kernel<<<dim3(512), 256, 0, stream>>>(Q, K1, K2, V1, V2, ATT);
  out_proj_kernel<<<dim3(8, 12), 256, 0, stream>>>(ATT, w_out, out);
}